// Round 1
// baseline (46479.782 us; speedup 1.0000x reference)
//
#include <hip/hip_runtime.h>
#include <hip/hip_cooperative_groups.h>
#include <math.h>

namespace cg = cooperative_groups;

// Problem dims (fixed by reference): N=64 batch, T=512 steps, D=512 in, H=512 hidden
constexpr int N_ = 64;
constexpr int T_ = 512;
constexpr int D_ = 512;
constexpr int H_ = 512;
constexpr int K4_ = 4 * H_;      // 2048 gate columns
constexpr int KTOT_ = D_ + H_;   // 1024 combined reduction dim

// ---------------------------------------------------------------------------
// Transpose Wx (D,4H) and Wh (H,4H) into WT (4H, D+H):
//   WT[k][d]      = Wx[d][k]   (d < D)
//   WT[k][D + dh] = Wh[dh][k]
// so each gate-column dot-product reads a contiguous row (float4-able).
// ---------------------------------------------------------------------------
__global__ __launch_bounds__(256) void transpose_w(const float* __restrict__ Wx,
                                                   const float* __restrict__ Wh,
                                                   float* __restrict__ WT) {
    __shared__ float tile[32][33];
    const int tk = blockIdx.x;   // k-tile: 0..63
    const int td = blockIdx.y;   // d-tile: 0..31
    const int lx = threadIdx.x;  // 0..31
    const int ly = threadIdx.y;  // 0..7

    #pragma unroll
    for (int i = 0; i < 4; ++i) {
        const int d = td * 32 + ly + i * 8;     // 0..1023 (combined)
        const int k = tk * 32 + lx;             // 0..2047
        float v;
        if (d < D_) v = Wx[(size_t)d * K4_ + k];
        else        v = Wh[(size_t)(d - D_) * K4_ + k];
        tile[ly + i * 8][lx] = v;
    }
    __syncthreads();
    #pragma unroll
    for (int i = 0; i < 4; ++i) {
        const int k = tk * 32 + ly + i * 8;
        const int d = td * 32 + lx;
        WT[(size_t)k * KTOT_ + d] = tile[lx][ly + i * 8];
    }
}

// ---------------------------------------------------------------------------
// Persistent cooperative LSTM kernel.
// Grid: 256 WGs x 256 threads (1 WG/CU). One grid.sync() per timestep.
//
// WG w: colgroup = w & 63 -> owns hidden cols [colgroup*8, colgroup*8+8)
//       ngroup   = w >> 6 -> owns batch rows  [ngroup*16, ngroup*16+16)
// Dot phase: thread -> j = wave*8 + (lane&7) in [0,32): gate = j>>3, hj = j&7,
//   nsub = lane>>3; computes a[n0+nsub][col] and a[n0+nsub+8][col], K=1024.
// Gate phase: threads 0..127 own one (n,hj) cell; c lives in a register
//   across the whole t-loop (no workspace needed for state).
// h_{t-1} is read from d_out (written at step t-1); h0 input at t=0.
// ---------------------------------------------------------------------------
__global__ __launch_bounds__(256) void lstm_persist(const float* __restrict__ x,
                                                    const float* __restrict__ h0,
                                                    const float* __restrict__ b,
                                                    const float* __restrict__ WT,
                                                    float* __restrict__ out) {
    cg::grid_group grid = cg::this_grid();

    const int wg = blockIdx.x;
    const int colgroup = wg & 63;
    const int ngroup = wg >> 6;
    const int hbase = colgroup * 8;   // hidden-col base, 0..504
    const int n0 = ngroup * 16;       // batch base, 0..48

    const int tid = threadIdx.x;
    const int wave = tid >> 6;
    const int lane = tid & 63;
    const int jc = lane & 7;
    const int nsub = lane >> 3;       // 0..7
    const int j = wave * 8 + jc;      // 0..31
    const int gate = j >> 3;          // 0..3
    const int hj = j & 7;             // 0..7
    const int col = gate * H_ + hbase + hj;   // global gate column, 0..2047

    const float4* __restrict__ wt4 = (const float4*)(WT + (size_t)col * KTOT_);
    const float bias = b[col];

    __shared__ float a_s[16][32];

    // gate-phase ownership (threads 0..127): cell (n0+gn, hbase+ghj)
    const int gn = tid >> 3;          // 0..31 (only <16 used)
    const int ghj = tid & 7;
    float c_reg = 0.0f;

    const int rowA = n0 + nsub;
    const int rowB = n0 + nsub + 8;
    const float4* __restrict__ xA = (const float4*)(x + (size_t)rowA * T_ * D_);
    const float4* __restrict__ xB = (const float4*)(x + (size_t)rowB * T_ * D_);

    for (int t = 0; t < T_; ++t) {
        float acc0 = bias, acc1 = bias;

        // ---- x part: K = 512 ----
        const float4* xa = xA + (size_t)t * (D_ / 4);
        const float4* xb = xB + (size_t)t * (D_ / 4);
        #pragma unroll 4
        for (int dc = 0; dc < D_ / 4; ++dc) {
            const float4 w = wt4[dc];
            const float4 va = xa[dc];
            const float4 vb = xb[dc];
            acc0 += va.x * w.x + va.y * w.y + va.z * w.z + va.w * w.w;
            acc1 += vb.x * w.x + vb.y * w.y + vb.z * w.z + vb.w * w.w;
        }

        // ---- h part: K = 512 ----
        const float4* ha;
        const float4* hb;
        if (t == 0) {
            ha = (const float4*)(h0 + (size_t)rowA * H_);
            hb = (const float4*)(h0 + (size_t)rowB * H_);
        } else {
            ha = (const float4*)(out + ((size_t)rowA * T_ + (t - 1)) * H_);
            hb = (const float4*)(out + ((size_t)rowB * T_ + (t - 1)) * H_);
        }
        const float4* __restrict__ wh4 = wt4 + (D_ / 4);
        #pragma unroll 4
        for (int dc = 0; dc < H_ / 4; ++dc) {
            const float4 w = wh4[dc];
            const float4 va = ha[dc];
            const float4 vb = hb[dc];
            acc0 += va.x * w.x + va.y * w.y + va.z * w.z + va.w * w.w;
            acc1 += vb.x * w.x + vb.y * w.y + vb.z * w.z + vb.w * w.w;
        }

        a_s[nsub][j] = acc0;
        a_s[nsub + 8][j] = acc1;
        __syncthreads();

        if (tid < 128) {
            const float ai = a_s[gn][0 + ghj];
            const float af = a_s[gn][8 + ghj];
            const float ao = a_s[gn][16 + ghj];
            const float ag = a_s[gn][24 + ghj];
            const float iv = 1.0f / (1.0f + expf(-ai));
            const float fv = 1.0f / (1.0f + expf(-af));
            const float ov = 1.0f / (1.0f + expf(-ao));
            const float gv = tanhf(ag);
            c_reg = fv * c_reg + iv * gv;
            const float hval = ov * tanhf(c_reg);
            out[((size_t)(n0 + gn) * T_ + t) * H_ + hbase + ghj] = hval;
        }

        __threadfence();   // make h_t visible device-wide (cross-XCD)
        grid.sync();       // all WGs see h_t before step t+1
    }
}

extern "C" void kernel_launch(void* const* d_in, const int* in_sizes, int n_in,
                              void* d_out, int out_size, void* d_ws, size_t ws_size,
                              hipStream_t stream) {
    const float* x  = (const float*)d_in[0];   // (N,T,D)
    const float* h0 = (const float*)d_in[1];   // (N,H)
    const float* Wx = (const float*)d_in[2];   // (D,4H)
    const float* Wh = (const float*)d_in[3];   // (H,4H)
    const float* b  = (const float*)d_in[4];   // (4H,)
    float* out = (float*)d_out;                // (N,T,H)
    float* WT = (float*)d_ws;                  // (4H, D+H) fp32 = 8 MB scratch

    // One-time weight transpose into workspace (needs 8 MB of d_ws).
    transpose_w<<<dim3(K4_ / 32, KTOT_ / 32), dim3(32, 8), 0, stream>>>(Wx, Wh, WT);

    void* kx = (void*)x; void* kh = (void*)h0; void* kb = (void*)b;
    void* kw = (void*)WT; void* ko = (void*)out;
    void* args[] = { &kx, &kh, &kb, &kw, &ko };
    hipLaunchCooperativeKernel((void*)lstm_persist, dim3(256), dim3(256), args, 0, stream);
}

// Round 2
// 32325.995 us; speedup vs baseline: 1.4378x; 1.4378x over previous
//
#include <hip/hip_runtime.h>
#include <hip/hip_cooperative_groups.h>
#include <math.h>

namespace cg = cooperative_groups;

// Problem dims (fixed): N=64, T=512, D=512, H=512, 4H=2048 gate cols.
constexpr int T_ = 512;
constexpr int D_ = 512;
constexpr int H_ = 512;
constexpr int V_ = 2048;            // gate columns (virtual-permuted: v = hdim*4 + gate)
constexpr int KW_ = 512;            // K for both Wx and Wh parts

using short8 = __attribute__((ext_vector_type(8))) short;   // 8 bf16 (4 VGPR) MFMA frag
using f32x4  = __attribute__((ext_vector_type(4))) float;   // MFMA accumulator

// Split fp32 -> bf16 hi + bf16 lo (x ~= hi + lo, captures ~17 bits of mantissa).
__device__ __forceinline__ void split_bf16(float x, unsigned short& hi, unsigned short& lo) {
    unsigned u  = __builtin_bit_cast(unsigned, x);
    unsigned rh = (u + 0x7fffu + ((u >> 16) & 1u)) >> 16;
    hi = (unsigned short)rh;
    float hf = __builtin_bit_cast(float, rh << 16);
    float l  = x - hf;                       // exact in fp32
    unsigned ul = __builtin_bit_cast(unsigned, l);
    unsigned rl = (ul + 0x7fffu + ((ul >> 16) & 1u)) >> 16;
    lo = (unsigned short)rl;
}

// ---------------------------------------------------------------------------
// prep_wt: W (512 x 2048 fp32, row-major) -> WT_hi/WT_lo bf16 [2048][512],
// with gate-permuted column order v = hdim*4 + gate (orig col o = gate*512+hdim)
// so the 4 gates of one hidden dim are adjacent in v.
// ---------------------------------------------------------------------------
__global__ __launch_bounds__(256) void prep_wt(const float* __restrict__ W,
                                               unsigned short* __restrict__ WT_hi,
                                               unsigned short* __restrict__ WT_lo) {
    __shared__ float tile[32][33];
    const int ot = blockIdx.x;          // o-tile (64)
    const int kt = blockIdx.y;          // k-tile (16)
    const int lx = threadIdx.x & 31;
    const int ly = threadIdx.x >> 5;    // 0..7
    #pragma unroll
    for (int i = 0; i < 4; ++i) {
        const int k = kt * 32 + ly + i * 8;
        const int o = ot * 32 + lx;
        tile[ly + i * 8][lx] = W[(size_t)k * V_ + o];   // coalesced in o
    }
    __syncthreads();
    #pragma unroll
    for (int i = 0; i < 4; ++i) {
        const int o = ot * 32 + ly + i * 8;
        const int v = ((o & 511) << 2) | (o >> 9);      // permuted col
        const int kk = kt * 32 + lx;
        unsigned short hi, lo;
        split_bf16(tile[lx][ly + i * 8], hi, lo);
        WT_hi[(size_t)v * KW_ + kk] = hi;               // coalesced in k
        WT_lo[(size_t)v * KW_ + kk] = lo;
    }
}

// prep_h0: split h0 (64x512 fp32) into hstage buffer 0 (hi at 0, lo at +32768).
__global__ __launch_bounds__(256) void prep_h0(const float* __restrict__ h0,
                                               unsigned short* __restrict__ hs) {
    const int i = blockIdx.x * 256 + threadIdx.x;   // 0..32767
    unsigned short hi, lo;
    split_bf16(h0[i], hi, lo);
    hs[i] = hi;
    hs[32768 + i] = lo;
}

// ---------------------------------------------------------------------------
// Main persistent cooperative kernel. Grid 256 WGs x 256 threads.
//
// Loop: for each chunk of CT steps:
//   phase A: all 1024 waves compute xw[tl][n][v] = x_t @ Wx + b  (split-bf16 MFMA,
//            wave-tile 16 rows x 64 v-cols, K=512), then grid.sync.
//   phase B (per step): WG (mt=wg>>6, cg=wg&63) computes rows [mt*16,+16) x
//            v-cols [cg*32,+32) of h@Wh via 2 16x16 tiles, K split over wave
//            pairs; + xw; gates on threads 0..127 (c in registers); h written
//            fp32 to out and split-bf16 to double-buffered hstage; grid.sync.
//
// hstage layout: [buf][hi/lo][64*512] bf16; step t reads buf t&1, writes (t+1)&1.
// ---------------------------------------------------------------------------
__global__ __launch_bounds__(256, 1) void lstm_main(const float* __restrict__ x,
                                                    const float* __restrict__ bias,
                                                    float* __restrict__ out,
                                                    const unsigned short* __restrict__ wxt,
                                                    const unsigned short* __restrict__ wht,
                                                    unsigned short* __restrict__ hs,
                                                    float* __restrict__ xw,
                                                    int CT) {
    cg::grid_group grid = cg::this_grid();

    const int tid  = threadIdx.x;
    const int wid  = tid >> 6;
    const int lane = tid & 63;
    const int kb   = lane >> 4;          // k-block 0..3 (8 elems each)
    const int mc   = lane & 15;          // M-row (A) or N-col (B/C) within tile

    const int wg = blockIdx.x;
    const int mt = wg >> 6;              // 0..3  (16-row group)
    const int cgp = wg & 63;             // 0..63 (32-vcol group)
    const int gw = wg * 4 + wid;         // global wave id 0..1023

    const int nt = wid & 1;              // phase B: which 16-col tile
    const int kh = wid >> 1;             // phase B: which K half

    __shared__ float red[8][64];
    __shared__ float a_s[16][33];

    float c_reg = 0.0f;                  // cell state for (n16,jj) of threads 0..127

    // phase B per-thread constants
    const int colvB = cgp * 32 + nt * 16 + mc;
    const unsigned short* bhpB = wht + (size_t)colvB * KW_ + kh * 256 + kb * 8;
    const unsigned short* blpB = bhpB + (size_t)V_ * KW_;   // wht_lo
    const int aoffB = (mt * 16 + mc) * KW_ + kh * 256 + kb * 8;

    for (int c0 = 0; c0 < T_; c0 += CT) {
        // ================= phase A: xw[tl][n][v] for tl in [0,CT) =================
        {
            const int tiles = CT * 128;               // (4*CT m-tiles) x (32 col64-groups)
            for (int idx = gw; idx < tiles; idx += 1024) {
                const int mtA = idx >> 5;             // 0..4CT-1
                const int ng  = idx & 31;             // 0..31
                const int rowA = mtA * 16 + mc;       // A-row (t-major,(t,n))
                const int tlA = rowA >> 6, nA = rowA & 63;
                const float* xrow = x + ((size_t)nA * T_ + (c0 + tlA)) * D_ + kb * 8;
                const unsigned short* bh0 = wxt + (size_t)(ng * 64 + mc) * KW_ + kb * 8;
                const unsigned short* bl0 = bh0 + (size_t)V_ * KW_;

                f32x4 acc[4] = {};
                #pragma unroll
                for (int ks = 0; ks < 16; ++ks) {
                    const float4 xa = *(const float4*)(xrow + ks * 32);
                    const float4 xb = *(const float4*)(xrow + ks * 32 + 4);
                    short8 ah, al;
                    {
                        unsigned short h0_, l0_;
                        split_bf16(xa.x, h0_, l0_); ah[0] = (short)h0_; al[0] = (short)l0_;
                        split_bf16(xa.y, h0_, l0_); ah[1] = (short)h0_; al[1] = (short)l0_;
                        split_bf16(xa.z, h0_, l0_); ah[2] = (short)h0_; al[2] = (short)l0_;
                        split_bf16(xa.w, h0_, l0_); ah[3] = (short)h0_; al[3] = (short)l0_;
                        split_bf16(xb.x, h0_, l0_); ah[4] = (short)h0_; al[4] = (short)l0_;
                        split_bf16(xb.y, h0_, l0_); ah[5] = (short)h0_; al[5] = (short)l0_;
                        split_bf16(xb.z, h0_, l0_); ah[6] = (short)h0_; al[6] = (short)l0_;
                        split_bf16(xb.w, h0_, l0_); ah[7] = (short)h0_; al[7] = (short)l0_;
                    }
                    #pragma unroll
                    for (int n2 = 0; n2 < 4; ++n2) {
                        const short8 bh = *(const short8*)(bh0 + n2 * 8192 + ks * 32);
                        const short8 bl = *(const short8*)(bl0 + n2 * 8192 + ks * 32);
                        acc[n2] = __builtin_amdgcn_mfma_f32_16x16x32_bf16(ah, bh, acc[n2], 0, 0, 0);
                        acc[n2] = __builtin_amdgcn_mfma_f32_16x16x32_bf16(ah, bl, acc[n2], 0, 0, 0);
                        acc[n2] = __builtin_amdgcn_mfma_f32_16x16x32_bf16(al, bh, acc[n2], 0, 0, 0);
                    }
                }
                // epilogue: + bias, store xw (C layout: col=lane&15, row=kb*4+j)
                #pragma unroll
                for (int n2 = 0; n2 < 4; ++n2) {
                    const int v = ng * 64 + n2 * 16 + mc;
                    const int o = ((v & 3) << 9) | (v >> 2);
                    const float bv = bias[o];
                    #pragma unroll
                    for (int j = 0; j < 4; ++j) {
                        const int r = mtA * 16 + kb * 4 + j;
                        const int tl2 = r >> 6, n2r = r & 63;
                        xw[((size_t)tl2 * 64 + n2r) * V_ + v] = acc[n2][j] + bv;
                    }
                }
            }
        }
        __threadfence();
        grid.sync();

        // ================= phase B: CT recurrent steps =================
        for (int tl = 0; tl < CT; ++tl) {
            const int t = c0 + tl;
            const unsigned short* hsrc = hs + (size_t)(t & 1) * 65536;   // hi; lo at +32768

            f32x4 acc = {};
            {
                const unsigned short* ah_p = hsrc + aoffB;
                const unsigned short* al_p = ah_p + 32768;
                #pragma unroll
                for (int ks = 0; ks < 8; ++ks) {
                    const short8 vah = *(const short8*)(ah_p + ks * 32);
                    const short8 val_ = *(const short8*)(al_p + ks * 32);
                    const short8 vbh = *(const short8*)(bhpB + ks * 32);
                    const short8 vbl = *(const short8*)(blpB + ks * 32);
                    acc = __builtin_amdgcn_mfma_f32_16x16x32_bf16(vah, vbh, acc, 0, 0, 0);
                    acc = __builtin_amdgcn_mfma_f32_16x16x32_bf16(vah, vbl, acc, 0, 0, 0);
                    acc = __builtin_amdgcn_mfma_f32_16x16x32_bf16(val_, vbh, acc, 0, 0, 0);
                    // advance B pointers along k inside index math (ks*32)
                }
            }
            // K-halves reduce
            if (kh == 1) {
                #pragma unroll
                for (int j = 0; j < 4; ++j) red[nt * 4 + j][lane] = acc[j];
            }
            __syncthreads();
            if (kh == 0) {
                const float* xwp = xw + (size_t)tl * 64 * V_;
                #pragma unroll
                for (int j = 0; j < 4; ++j) {
                    const int r16 = kb * 4 + j;
                    const int nn = mt * 16 + r16;
                    float a = acc[j] + red[nt * 4 + j][lane] + xwp[(size_t)nn * V_ + colvB];
                    a_s[r16][nt * 16 + mc] = a;
                }
            }
            __syncthreads();
            // gates: threads 0..127 own (n16 = tid>>3, jj = tid&7)
            if (tid < 128) {
                const int n16 = tid >> 3, jj = tid & 7;
                const float ai = a_s[n16][jj * 4 + 0];
                const float af = a_s[n16][jj * 4 + 1];
                const float ao = a_s[n16][jj * 4 + 2];
                const float ag = a_s[n16][jj * 4 + 3];
                const float iv = 1.0f / (1.0f + __expf(-ai));
                const float fv = 1.0f / (1.0f + __expf(-af));
                const float ov = 1.0f / (1.0f + __expf(-ao));
                const float gv = tanhf(ag);
                c_reg = fv * c_reg + iv * gv;
                const float hval = ov * tanhf(c_reg);
                const int n = mt * 16 + n16;
                const int hd = cgp * 8 + jj;
                out[((size_t)n * T_ + t) * H_ + hd] = hval;
                unsigned short hh, hl;
                split_bf16(hval, hh, hl);
                unsigned short* hdst = hs + (size_t)((t + 1) & 1) * 65536;
                hdst[n * KW_ + hd] = hh;
                hdst[32768 + n * KW_ + hd] = hl;
            }
            __threadfence();
            grid.sync();
        }
    }
}

extern "C" void kernel_launch(void* const* d_in, const int* in_sizes, int n_in,
                              void* d_out, int out_size, void* d_ws, size_t ws_size,
                              hipStream_t stream) {
    const float* x  = (const float*)d_in[0];   // (N,T,D)
    const float* h0 = (const float*)d_in[1];   // (N,H)
    const float* Wx = (const float*)d_in[2];   // (D,4H)
    const float* Wh = (const float*)d_in[3];   // (H,4H)
    const float* b  = (const float*)d_in[4];   // (4H,)
    float* out = (float*)d_out;                // (N,T,H)

    // ws layout:
    //   [0,2MB)   WxT_hi bf16 [2048][512]
    //   [2,4MB)   WxT_lo
    //   [4,6MB)   WhT_hi
    //   [6,8MB)   WhT_lo
    //   [8MB, +256KB) hstage [2 bufs][hi/lo][64*512] bf16
    //   [8MB+256KB, ...) xw chunk buffer fp32 [CT][64][2048]
    char* ws = (char*)d_ws;
    unsigned short* wxt = (unsigned short*)ws;                       // hi; lo at +1048576 elems
    unsigned short* wht = (unsigned short*)(ws + 4u * 1024 * 1024);
    unsigned short* hs  = (unsigned short*)(ws + 8u * 1024 * 1024);
    float* xw           = (float*)(ws + 8u * 1024 * 1024 + 256u * 1024);

    const size_t fixed = 8u * 1024 * 1024 + 256u * 1024;
    int CT = 8;
    const int cands[7] = {512, 256, 128, 64, 32, 16, 8};
    for (int i = 0; i < 7; ++i) {
        if (fixed + (size_t)cands[i] * 64 * 2048 * 4 <= ws_size) { CT = cands[i]; break; }
    }

    prep_wt<<<dim3(64, 16), 256, 0, stream>>>(Wx, wxt, wxt + (size_t)2048 * 512);
    prep_wt<<<dim3(64, 16), 256, 0, stream>>>(Wh, wht, wht + (size_t)2048 * 512);
    prep_h0<<<128, 256, 0, stream>>>(h0, hs);

    void* kx = (void*)x; void* kb_ = (void*)b; void* ko = (void*)out;
    void* kwx = (void*)wxt; void* kwh = (void*)wht; void* khs = (void*)hs;
    void* kxw = (void*)xw;
    void* args[] = { &kx, &kb_, &ko, &kwx, &kwh, &khs, &kxw, &CT };
    hipLaunchCooperativeKernel((void*)lstm_main, dim3(256), dim3(256), args, 0, stream);
}

// Round 4
// 11758.450 us; speedup vs baseline: 3.9529x; 2.7492x over previous
//
#include <hip/hip_runtime.h>
#include <math.h>

// Problem dims (fixed): N=64, T=512, D=512, H=512, 4H=2048 gate cols.
// Gate-col permutation: v = hd*4 + gate  (orig col o = gate*512 + hd)
constexpr int T_ = 512;
constexpr int H_ = 512;
constexpr int V_ = 2048;
constexpr int KW_ = 512;

using short8 = __attribute__((ext_vector_type(8))) short;     // 8 bf16 MFMA frag
using f32x4  = __attribute__((ext_vector_type(4))) float;     // MFMA accumulator
using u16x4  = __attribute__((ext_vector_type(4))) unsigned short;
using u16x8  = __attribute__((ext_vector_type(8))) unsigned short;

// ws layout (bytes):
//   [0, 4MB)        WxT bf16: hi [2048][512] then lo (each 2MB)
//   [4MB, 8MB)      WhT bf16: hi then lo
//   [8MB, +256KB)   hstage: [2 parities][hi 64KB | lo 64KB] of h[64][512] bf16
//   [+128KB)        cs: fp32 c[64][512]
//   xs: bf16 split x chunk: hi [CT*64][512] then lo     (CT*128KB)
//   xw: fp32 [CT*64][2048]                              (CT*512KB)
constexpr size_t OFF_WXT = 0;
constexpr size_t OFF_WHT = 4u * 1024 * 1024;
constexpr size_t OFF_HS  = 8u * 1024 * 1024;
constexpr size_t OFF_CS  = OFF_HS + 256u * 1024;
constexpr size_t OFF_XS  = OFF_CS + 128u * 1024;

__device__ __forceinline__ void split_bf16(float x, unsigned short& hi, unsigned short& lo) {
    unsigned u  = __builtin_bit_cast(unsigned, x);
    unsigned rh = (u + 0x7fffu + ((u >> 16) & 1u)) >> 16;
    hi = (unsigned short)rh;
    float hf = __builtin_bit_cast(float, rh << 16);
    float l  = x - hf;                       // exact in fp32
    unsigned ul = __builtin_bit_cast(unsigned, l);
    unsigned rl = (ul + 0x7fffu + ((ul >> 16) & 1u)) >> 16;
    lo = (unsigned short)rl;
}

__device__ __forceinline__ float sigm(float x) { return 1.0f / (1.0f + __expf(-x)); }
__device__ __forceinline__ float tanh_fast(float x) {
    float xc = fminf(fmaxf(x, -15.0f), 15.0f);
    float e = __expf(-2.0f * xc);
    return (1.0f - e) / (1.0f + e);
}

// ---------------------------------------------------------------------------
// prep_wt: W (512 x 2048 fp32) -> WT_hi/WT_lo bf16 [2048][512], v-permuted cols.
// (validated in Round 2)
// ---------------------------------------------------------------------------
__global__ __launch_bounds__(256) void prep_wt(const float* __restrict__ W,
                                               unsigned short* __restrict__ WT_hi,
                                               unsigned short* __restrict__ WT_lo) {
    __shared__ float tile[32][33];
    const int ot = blockIdx.x;          // o-tile (64)
    const int kt = blockIdx.y;          // k-tile (16)
    const int lx = threadIdx.x;         // 0..31
    const int ly = threadIdx.y;         // 0..7
    #pragma unroll
    for (int i = 0; i < 4; ++i) {
        const int k = kt * 32 + ly + i * 8;
        const int o = ot * 32 + lx;
        tile[ly + i * 8][lx] = W[(size_t)k * V_ + o];
    }
    __syncthreads();
    #pragma unroll
    for (int i = 0; i < 4; ++i) {
        const int o = ot * 32 + ly + i * 8;
        const int v = ((o & 511) << 2) | (o >> 9);
        const int kk = kt * 32 + lx;
        unsigned short hi, lo;
        split_bf16(tile[lx][ly + i * 8], hi, lo);
        WT_hi[(size_t)v * KW_ + kk] = hi;
        WT_lo[(size_t)v * KW_ + kk] = lo;
    }
}

// prep_h0: split h0 into hstage parity-0; zero cs. (runs every launch -> replay-safe)
__global__ __launch_bounds__(256) void prep_h0(const float* __restrict__ h0,
                                               unsigned short* __restrict__ hs,
                                               float* __restrict__ cs) {
    const int i = blockIdx.x * 256 + threadIdx.x;   // 0..32767
    unsigned short hi, lo;
    split_bf16(h0[i], hi, lo);
    hs[i] = hi;
    hs[32768 + i] = lo;
    cs[i] = 0.0f;
}

// ---------------------------------------------------------------------------
// xsplit: split x chunk [c0, c0+CT) into xs hi/lo bf16, rows r = tl*64 + n.
// ---------------------------------------------------------------------------
__global__ __launch_bounds__(256) void xsplit(const float* __restrict__ x,
                                              unsigned short* __restrict__ xs,
                                              int c0, int CT) {
    const int gtid = blockIdx.x * 256 + threadIdx.x;
    const size_t xs_lo = (size_t)CT * 32768;
    const int tot = CT * 4096;                   // units of 8 elems
    for (int i = gtid; i < tot; i += 65536) {
        const int r  = i >> 6;
        const int d8 = (i & 63) << 3;
        const int n = r & 63, tl = r >> 6;
        const float* xp = x + ((size_t)n * T_ + (c0 + tl)) * 512 + d8;
        const float4 va = *(const float4*)xp;
        const float4 vb = *(const float4*)(xp + 4);
        unsigned short hh[8], ll[8];
        split_bf16(va.x, hh[0], ll[0]); split_bf16(va.y, hh[1], ll[1]);
        split_bf16(va.z, hh[2], ll[2]); split_bf16(va.w, hh[3], ll[3]);
        split_bf16(vb.x, hh[4], ll[4]); split_bf16(vb.y, hh[5], ll[5]);
        split_bf16(vb.z, hh[6], ll[6]); split_bf16(vb.w, hh[7], ll[7]);
        u16x8 vh = {hh[0],hh[1],hh[2],hh[3],hh[4],hh[5],hh[6],hh[7]};
        u16x8 vl = {ll[0],ll[1],ll[2],ll[3],ll[4],ll[5],ll[6],ll[7]};
        *(u16x8*)(xs + (size_t)r * 512 + d8) = vh;
        *(u16x8*)(xs + xs_lo + (size_t)r * 512 + d8) = vl;
    }
}

// ---------------------------------------------------------------------------
// xw_gemm: xw[r][v] = xs[r][:] @ WxT[v][:] + b[v]   (split-bf16, 3-product)
// grid 256 x 256; wave handles 16-row x 64-col tiles, K=512.
// ---------------------------------------------------------------------------
__global__ __launch_bounds__(256) void xw_gemm(const unsigned short* __restrict__ xs,
                                               const unsigned short* __restrict__ wxt,
                                               const float* __restrict__ bias,
                                               float* __restrict__ xw, int CT) {
    const int tid = threadIdx.x;
    const int wid = tid >> 6, lane = tid & 63;
    const int mc = lane & 15, kb = lane >> 4;
    const int gwave = blockIdx.x * 4 + wid;
    const size_t xs_lo = (size_t)CT * 32768;

    const int tiles = CT * 128;
    for (int idx = gwave; idx < tiles; idx += 1024) {
        const int mtA = idx >> 5;
        const int ng  = idx & 31;
        const short* pa  = (const short*)xs + (size_t)(mtA * 16 + mc) * 512 + kb * 8;
        const short* pal = pa + xs_lo;
        const short* pb  = (const short*)wxt + (size_t)(ng * 64 + mc) * KW_ + kb * 8;
        f32x4 acc[4] = {};
        #pragma unroll
        for (int ks = 0; ks < 16; ++ks) {
            const short8 Ah = *(const short8*)(pa + ks * 32);
            const short8 Al = *(const short8*)(pal + ks * 32);
            #pragma unroll
            for (int n2 = 0; n2 < 4; ++n2) {
                const short8 bh = *(const short8*)(pb + (size_t)n2 * 8192 + ks * 32);
                const short8 bl = *(const short8*)(pb + 1048576 + (size_t)n2 * 8192 + ks * 32);
                acc[n2] = __builtin_amdgcn_mfma_f32_16x16x32_bf16(Ah, bh, acc[n2], 0, 0, 0);
                acc[n2] = __builtin_amdgcn_mfma_f32_16x16x32_bf16(Al, bh, acc[n2], 0, 0, 0);
                acc[n2] = __builtin_amdgcn_mfma_f32_16x16x32_bf16(Ah, bl, acc[n2], 0, 0, 0);
            }
        }
        #pragma unroll
        for (int n2 = 0; n2 < 4; ++n2) {
            const int v = ng * 64 + n2 * 16 + mc;
            const float bv = bias[((v & 3) << 9) | (v >> 2)];
            #pragma unroll
            for (int j = 0; j < 4; ++j) {
                const int r = mtA * 16 + kb * 4 + j;
                xw[(size_t)r * V_ + v] = acc[n2][j] + bv;
            }
        }
    }
}

// ---------------------------------------------------------------------------
// lstm_step: one recurrent step. 32 WGs x 256 thr. WG wg owns v-cols
// [wg*64, +64) x all 64 batch rows. a = h_{t-1} @ WhT + xw[tl]; gates;
// write out[:,t,hd16] fp32 + h split-bf16 into hstage parity (t+1)&1;
// c state in cs (fp32, same thread reads/writes its own cells).
// Plain loads/stores everywhere — kernel boundary provides all ordering.
// ---------------------------------------------------------------------------
__global__ __launch_bounds__(256) void lstm_step(const unsigned short* __restrict__ wht,
                                                 unsigned short* __restrict__ hs,
                                                 float* __restrict__ cs,
                                                 const float* __restrict__ xw,
                                                 float* __restrict__ out,
                                                 int t, int tl) {
    const int tid = threadIdx.x;
    const int wid = tid >> 6, lane = tid & 63;
    const int mc = lane & 15, kb = lane >> 4;
    const int wg = blockIdx.x;           // 0..31
    const int v0 = wg * 64;

    __shared__ float a_s[64][68];

    const short* ha = (const short*)(hs + (size_t)(t & 1) * 65536)
                      + (size_t)(wid * 16 + mc) * 512 + kb * 8;
    const short* hl = ha + 32768;
    const short* Bp0 = (const short*)wht + (size_t)(v0 + mc) * KW_ + kb * 8;

    f32x4 acc[4] = {};
    #pragma unroll
    for (int ks = 0; ks < 16; ++ks) {
        const short8 Ah = *(const short8*)(ha + ks * 32);
        const short8 Al = *(const short8*)(hl + ks * 32);
        #pragma unroll
        for (int nt = 0; nt < 4; ++nt) {
            const short8 bh = *(const short8*)(Bp0 + (size_t)nt * 8192 + ks * 32);
            const short8 bl = *(const short8*)(Bp0 + 1048576 + (size_t)nt * 8192 + ks * 32);
            acc[nt] = __builtin_amdgcn_mfma_f32_16x16x32_bf16(Ah, bh, acc[nt], 0, 0, 0);
            acc[nt] = __builtin_amdgcn_mfma_f32_16x16x32_bf16(Al, bh, acc[nt], 0, 0, 0);
            acc[nt] = __builtin_amdgcn_mfma_f32_16x16x32_bf16(Ah, bl, acc[nt], 0, 0, 0);
        }
    }
    // epilogue: a (+xw) into LDS.  acc[nt][j] = a[batch = wid*16+kb*4+j][v0 + nt*16+mc]
    {
        const float* xwr = xw + (size_t)(tl * 64 + wid * 16 + kb * 4) * V_ + v0;
        #pragma unroll
        for (int nt = 0; nt < 4; ++nt)
            #pragma unroll
            for (int j = 0; j < 4; ++j)
                a_s[wid * 16 + kb * 4 + j][nt * 16 + mc] =
                    acc[nt][j] + xwr[(size_t)j * V_ + nt * 16 + mc];
    }
    __syncthreads();
    // gates: thread owns batch gn = tid>>2, hd quad gq = tid&3 -> hd = wg*16+gq*4+m
    {
        const int gn = tid >> 2, gq = tid & 3;
        const float4* ap = (const float4*)&a_s[gn][gq * 16];
        float* cp = cs + (size_t)gn * 512 + wg * 16 + gq * 4;
        float4 cold = *(const float4*)cp;
        float cv[4], hv[4];
        #pragma unroll
        for (int m = 0; m < 4; ++m) {
            const float4 g4 = ap[m];
            const float iv = sigm(g4.x);
            const float fv = sigm(g4.y);
            const float ov = sigm(g4.z);
            const float gv = tanh_fast(g4.w);
            const float co = (m == 0) ? cold.x : (m == 1) ? cold.y : (m == 2) ? cold.z : cold.w;
            const float cc = fv * co + iv * gv;
            cv[m] = cc;
            hv[m] = ov * tanh_fast(cc);
        }
        *(float4*)cp = make_float4(cv[0], cv[1], cv[2], cv[3]);
        *(float4*)(out + (size_t)gn * T_ * H_ + (size_t)t * H_ + wg * 16 + gq * 4) =
            make_float4(hv[0], hv[1], hv[2], hv[3]);
        unsigned short hh[4], hl4[4];
        #pragma unroll
        for (int m = 0; m < 4; ++m) split_bf16(hv[m], hh[m], hl4[m]);
        u16x4 vh = {hh[0], hh[1], hh[2], hh[3]};
        u16x4 vl = {hl4[0], hl4[1], hl4[2], hl4[3]};
        unsigned short* hdst = hs + (size_t)((t + 1) & 1) * 65536 + (size_t)gn * 512 + wg * 16 + gq * 4;
        *(u16x4*)hdst = vh;
        *(u16x4*)(hdst + 32768) = vl;
    }
}

extern "C" void kernel_launch(void* const* d_in, const int* in_sizes, int n_in,
                              void* d_out, int out_size, void* d_ws, size_t ws_size,
                              hipStream_t stream) {
    const float* x  = (const float*)d_in[0];   // (N,T,D)
    const float* h0 = (const float*)d_in[1];   // (N,H)
    const float* Wx = (const float*)d_in[2];   // (D,4H)
    const float* Wh = (const float*)d_in[3];   // (H,4H)
    const float* b  = (const float*)d_in[4];   // (4H,)
    float* out = (float*)d_out;                // (N,T,H)

    char* ws = (char*)d_ws;
    unsigned short* wxt = (unsigned short*)(ws + OFF_WXT);   // hi; lo at +1048576 elems
    unsigned short* wht = (unsigned short*)(ws + OFF_WHT);
    unsigned short* hs  = (unsigned short*)(ws + OFF_HS);
    float* cs           = (float*)(ws + OFF_CS);
    unsigned short* xs  = (unsigned short*)(ws + OFF_XS);

    // pick largest chunk CT that fits: xs = CT*128KB, xw = CT*512KB
    int CT = 8;
    const int cands[4] = {64, 32, 16, 8};
    for (int i = 0; i < 4; ++i) {
        size_t need = OFF_XS + (size_t)cands[i] * (131072 + 524288);
        if (need <= ws_size) { CT = cands[i]; break; }
    }
    float* xw = (float*)(ws + OFF_XS + (size_t)CT * 131072);

    prep_wt<<<dim3(64, 16), dim3(32, 8), 0, stream>>>(Wx, wxt, wxt + (size_t)V_ * KW_);
    prep_wt<<<dim3(64, 16), dim3(32, 8), 0, stream>>>(Wh, wht, wht + (size_t)V_ * KW_);
    prep_h0<<<128, 256, 0, stream>>>(h0, hs, cs);

    for (int c0 = 0; c0 < T_; c0 += CT) {
        xsplit<<<256, 256, 0, stream>>>(x, xs, c0, CT);
        xw_gemm<<<256, 256, 0, stream>>>(xs, wxt, b, xw, CT);
        for (int tl = 0; tl < CT; ++tl) {
            lstm_step<<<32, 256, 0, stream>>>(wht, hs, cs, xw, out, c0 + tl, tl);
        }
    }
}

// Round 5
// 5919.326 us; speedup vs baseline: 7.8522x; 1.9865x over previous
//
#include <hip/hip_runtime.h>
#include <math.h>

// Problem dims (fixed): N=64, T=512, D=512, H=512, 4H=2048 gate cols.
// Gate-col permutation: v = hd*4 + gate  (orig col o = gate*512 + hd)
constexpr int T_ = 512;
constexpr int H_ = 512;
constexpr int V_ = 2048;
constexpr int KW_ = 512;

using short8 = __attribute__((ext_vector_type(8))) short;     // 8 bf16 MFMA frag
using f32x4  = __attribute__((ext_vector_type(4))) float;     // MFMA accumulator
using u16x8  = __attribute__((ext_vector_type(8))) unsigned short;

// ws layout (bytes):
//   [0, 4MB)        WxT bf16: hi [2048][512] then lo (each 2MB)
//   [4MB, 8MB)      WhT bf16: hi then lo
//   [8MB, +256KB)   hstage: [2 parities][hi 64KB | lo 64KB] of h[64][512] bf16
//   [+128KB)        cs: fp32 c[64][512]
//   xs: bf16 split x chunk: hi [CT*64][512] then lo     (CT*128KB)
//   xw: fp32 [CT*64][2048]                              (CT*512KB)
constexpr size_t OFF_WXT = 0;
constexpr size_t OFF_WHT = 4u * 1024 * 1024;
constexpr size_t OFF_HS  = 8u * 1024 * 1024;
constexpr size_t OFF_CS  = OFF_HS + 256u * 1024;
constexpr size_t OFF_XS  = OFF_CS + 128u * 1024;

__device__ __forceinline__ void split_bf16(float x, unsigned short& hi, unsigned short& lo) {
    unsigned u  = __builtin_bit_cast(unsigned, x);
    unsigned rh = (u + 0x7fffu + ((u >> 16) & 1u)) >> 16;
    hi = (unsigned short)rh;
    float hf = __builtin_bit_cast(float, rh << 16);
    float l  = x - hf;                       // exact in fp32
    unsigned ul = __builtin_bit_cast(unsigned, l);
    unsigned rl = (ul + 0x7fffu + ((ul >> 16) & 1u)) >> 16;
    lo = (unsigned short)rl;
}

__device__ __forceinline__ float sigm(float x) { return 1.0f / (1.0f + __expf(-x)); }
__device__ __forceinline__ float tanh_fast(float x) {
    float xc = fminf(fmaxf(x, -15.0f), 15.0f);
    float e = __expf(-2.0f * xc);
    return (1.0f - e) / (1.0f + e);
}

// ---------------------------------------------------------------------------
// prep_wt: W (512 x 2048 fp32) -> WT_hi/WT_lo bf16 [2048][512], v-permuted cols.
// (validated in Rounds 2/4)
// ---------------------------------------------------------------------------
__global__ __launch_bounds__(256) void prep_wt(const float* __restrict__ W,
                                               unsigned short* __restrict__ WT_hi,
                                               unsigned short* __restrict__ WT_lo) {
    __shared__ float tile[32][33];
    const int ot = blockIdx.x;          // o-tile (64)
    const int kt = blockIdx.y;          // k-tile (16)
    const int lx = threadIdx.x;         // 0..31
    const int ly = threadIdx.y;         // 0..7
    #pragma unroll
    for (int i = 0; i < 4; ++i) {
        const int k = kt * 32 + ly + i * 8;
        const int o = ot * 32 + lx;
        tile[ly + i * 8][lx] = W[(size_t)k * V_ + o];
    }
    __syncthreads();
    #pragma unroll
    for (int i = 0; i < 4; ++i) {
        const int o = ot * 32 + ly + i * 8;
        const int v = ((o & 511) << 2) | (o >> 9);
        const int kk = kt * 32 + lx;
        unsigned short hi, lo;
        split_bf16(tile[lx][ly + i * 8], hi, lo);
        WT_hi[(size_t)v * KW_ + kk] = hi;
        WT_lo[(size_t)v * KW_ + kk] = lo;
    }
}

// prep_h0: split h0 into hstage parity-0; zero cs. (runs every launch -> replay-safe)
__global__ __launch_bounds__(256) void prep_h0(const float* __restrict__ h0,
                                               unsigned short* __restrict__ hs,
                                               float* __restrict__ cs) {
    const int i = blockIdx.x * 256 + threadIdx.x;   // 0..32767
    unsigned short hi, lo;
    split_bf16(h0[i], hi, lo);
    hs[i] = hi;
    hs[32768 + i] = lo;
    cs[i] = 0.0f;
}

// ---------------------------------------------------------------------------
// xsplit: split x chunk [c0, c0+CT) into xs hi/lo bf16, rows r = tl*64 + n.
// ---------------------------------------------------------------------------
__global__ __launch_bounds__(256) void xsplit(const float* __restrict__ x,
                                              unsigned short* __restrict__ xs,
                                              int c0, int CT) {
    const int gtid = blockIdx.x * 256 + threadIdx.x;
    const size_t xs_lo = (size_t)CT * 32768;
    const int tot = CT * 4096;                   // units of 8 elems
    for (int i = gtid; i < tot; i += 65536) {
        const int r  = i >> 6;
        const int d8 = (i & 63) << 3;
        const int n = r & 63, tl = r >> 6;
        const float* xp = x + ((size_t)n * T_ + (c0 + tl)) * 512 + d8;
        const float4 va = *(const float4*)xp;
        const float4 vb = *(const float4*)(xp + 4);
        unsigned short hh[8], ll[8];
        split_bf16(va.x, hh[0], ll[0]); split_bf16(va.y, hh[1], ll[1]);
        split_bf16(va.z, hh[2], ll[2]); split_bf16(va.w, hh[3], ll[3]);
        split_bf16(vb.x, hh[4], ll[4]); split_bf16(vb.y, hh[5], ll[5]);
        split_bf16(vb.z, hh[6], ll[6]); split_bf16(vb.w, hh[7], ll[7]);
        u16x8 vh = {hh[0],hh[1],hh[2],hh[3],hh[4],hh[5],hh[6],hh[7]};
        u16x8 vl = {ll[0],ll[1],ll[2],ll[3],ll[4],ll[5],ll[6],ll[7]};
        *(u16x8*)(xs + (size_t)r * 512 + d8) = vh;
        *(u16x8*)(xs + xs_lo + (size_t)r * 512 + d8) = vl;
    }
}

// ---------------------------------------------------------------------------
// xw_gemm: xw[r][v] = xs[r][:] @ WxT[v][:] + b[v]   (split-bf16, 3-product)
// grid 256 x 256; wave handles 16-row x 64-col tiles, K=512.
// ---------------------------------------------------------------------------
__global__ __launch_bounds__(256) void xw_gemm(const unsigned short* __restrict__ xs,
                                               const unsigned short* __restrict__ wxt,
                                               const float* __restrict__ bias,
                                               float* __restrict__ xw, int CT) {
    const int tid = threadIdx.x;
    const int wid = tid >> 6, lane = tid & 63;
    const int mc = lane & 15, kb = lane >> 4;
    const int gwave = blockIdx.x * 4 + wid;
    const size_t xs_lo = (size_t)CT * 32768;

    const int tiles = CT * 128;
    for (int idx = gwave; idx < tiles; idx += 1024) {
        const int mtA = idx >> 5;
        const int ng  = idx & 31;
        const short* pa  = (const short*)xs + (size_t)(mtA * 16 + mc) * 512 + kb * 8;
        const short* pal = pa + xs_lo;
        const short* pb  = (const short*)wxt + (size_t)(ng * 64 + mc) * KW_ + kb * 8;
        f32x4 acc[4] = {};
        #pragma unroll
        for (int ks = 0; ks < 16; ++ks) {
            const short8 Ah = *(const short8*)(pa + ks * 32);
            const short8 Al = *(const short8*)(pal + ks * 32);
            #pragma unroll
            for (int n2 = 0; n2 < 4; ++n2) {
                const short8 bh = *(const short8*)(pb + (size_t)n2 * 8192 + ks * 32);
                const short8 bl = *(const short8*)(pb + 1048576 + (size_t)n2 * 8192 + ks * 32);
                acc[n2] = __builtin_amdgcn_mfma_f32_16x16x32_bf16(Ah, bh, acc[n2], 0, 0, 0);
                acc[n2] = __builtin_amdgcn_mfma_f32_16x16x32_bf16(Al, bh, acc[n2], 0, 0, 0);
                acc[n2] = __builtin_amdgcn_mfma_f32_16x16x32_bf16(Ah, bl, acc[n2], 0, 0, 0);
            }
        }
        #pragma unroll
        for (int n2 = 0; n2 < 4; ++n2) {
            const int v = ng * 64 + n2 * 16 + mc;
            const float bv = bias[((v & 3) << 9) | (v >> 2)];
            #pragma unroll
            for (int j = 0; j < 4; ++j) {
                const int r = mtA * 16 + kb * 4 + j;
                xw[(size_t)r * V_ + v] = acc[n2][j] + bv;
            }
        }
    }
}

// ---------------------------------------------------------------------------
// lstm_step v2: one recurrent step. 64 WGs x 256 thr.
// WG wg owns v-cols [wg*32, +32) x all 64 batch rows. K=512 split across the
// 4 waves (wave wid: k in [wid*128, +128) -> only 4 serial K-iterations).
// Partial sums reduced via LDS red[4][64][33]; gates on all 256 threads
// (thread -> row r = tid>>2, hd quads qq & qq+4). c in cs (fp32).
// Plain loads/stores; kernel boundary provides all cross-step ordering.
// ---------------------------------------------------------------------------
__global__ __launch_bounds__(256) void lstm_step(const unsigned short* __restrict__ wht,
                                                 unsigned short* __restrict__ hs,
                                                 float* __restrict__ cs,
                                                 const float* __restrict__ xw,
                                                 float* __restrict__ out,
                                                 int t, int tl) {
    const int tid = threadIdx.x;
    const int wid = tid >> 6, lane = tid & 63;
    const int mc = lane & 15, kb = lane >> 4;
    const int wg = blockIdx.x;           // 0..63

    __shared__ float red[4][64][33];

    const short* hbase = (const short*)(hs + (size_t)(t & 1) * 65536);
    const short* whb = (const short*)wht;
    const int k0 = wid * 128;            // this wave's K-quarter

    f32x4 acc[4][2] = {};
    #pragma unroll
    for (int ks = 0; ks < 4; ++ks) {
        const int koff = k0 + ks * 32 + kb * 8;
        short8 Bh[2], Bl[2];
        #pragma unroll
        for (int nt = 0; nt < 2; ++nt) {
            const size_t bo = (size_t)(wg * 32 + nt * 16 + mc) * KW_ + koff;
            Bh[nt] = *(const short8*)(whb + bo);
            Bl[nt] = *(const short8*)(whb + 1048576 + bo);
        }
        #pragma unroll
        for (int rt = 0; rt < 4; ++rt) {
            const size_t ao = (size_t)(rt * 16 + mc) * KW_ + koff;
            const short8 Ah = *(const short8*)(hbase + ao);
            const short8 Al = *(const short8*)(hbase + 32768 + ao);
            #pragma unroll
            for (int nt = 0; nt < 2; ++nt) {
                acc[rt][nt] = __builtin_amdgcn_mfma_f32_16x16x32_bf16(Ah, Bh[nt], acc[rt][nt], 0, 0, 0);
                acc[rt][nt] = __builtin_amdgcn_mfma_f32_16x16x32_bf16(Al, Bh[nt], acc[rt][nt], 0, 0, 0);
                acc[rt][nt] = __builtin_amdgcn_mfma_f32_16x16x32_bf16(Ah, Bl[nt], acc[rt][nt], 0, 0, 0);
            }
        }
    }
    // write K-quarter partials: C layout row = kb*4+j (within tile), col = mc
    #pragma unroll
    for (int rt = 0; rt < 4; ++rt)
        #pragma unroll
        for (int nt = 0; nt < 2; ++nt)
            #pragma unroll
            for (int j = 0; j < 4; ++j)
                red[wid][rt * 16 + kb * 4 + j][nt * 16 + mc] = acc[rt][nt][j];
    __syncthreads();

    // gates: thread owns row r = tid>>2, hd quads q = qq and qq+4 (hd = wg*8+q)
    const int r = tid >> 2, qq = tid & 3;
    const float* xwr = xw + ((size_t)tl * 64 + r) * V_ + wg * 32;
    float* cp = cs + (size_t)r * 512 + wg * 8;
    float* op = out + ((size_t)r * T_ + t) * H_ + wg * 8;
    unsigned short* hdst = hs + (size_t)((t + 1) & 1) * 65536 + (size_t)r * 512 + wg * 8;
    #pragma unroll
    for (int half = 0; half < 2; ++half) {
        const int q = qq + half * 4;
        float a[4];
        #pragma unroll
        for (int c2 = 0; c2 < 4; ++c2)
            a[c2] = red[0][r][q * 4 + c2] + red[1][r][q * 4 + c2]
                  + red[2][r][q * 4 + c2] + red[3][r][q * 4 + c2];
        const float4 xv = *(const float4*)(xwr + q * 4);
        const float iv = sigm(a[0] + xv.x);
        const float fv = sigm(a[1] + xv.y);
        const float ov = sigm(a[2] + xv.z);
        const float gv = tanh_fast(a[3] + xv.w);
        const float cc = fv * cp[q] + iv * gv;
        cp[q] = cc;
        const float hv = ov * tanh_fast(cc);
        op[q] = hv;
        unsigned short hh, hl;
        split_bf16(hv, hh, hl);
        hdst[q] = hh;
        hdst[32768 + q] = hl;
    }
}

extern "C" void kernel_launch(void* const* d_in, const int* in_sizes, int n_in,
                              void* d_out, int out_size, void* d_ws, size_t ws_size,
                              hipStream_t stream) {
    const float* x  = (const float*)d_in[0];   // (N,T,D)
    const float* h0 = (const float*)d_in[1];   // (N,H)
    const float* Wx = (const float*)d_in[2];   // (D,4H)
    const float* Wh = (const float*)d_in[3];   // (H,4H)
    const float* b  = (const float*)d_in[4];   // (4H,)
    float* out = (float*)d_out;                // (N,T,H)

    char* ws = (char*)d_ws;
    unsigned short* wxt = (unsigned short*)(ws + OFF_WXT);   // hi; lo at +1048576 elems
    unsigned short* wht = (unsigned short*)(ws + OFF_WHT);
    unsigned short* hs  = (unsigned short*)(ws + OFF_HS);
    float* cs           = (float*)(ws + OFF_CS);
    unsigned short* xs  = (unsigned short*)(ws + OFF_XS);

    // pick largest chunk CT that fits: xs = CT*128KB, xw = CT*512KB
    int CT = 8;
    const int cands[7] = {512, 256, 128, 64, 32, 16, 8};
    for (int i = 0; i < 7; ++i) {
        size_t need = OFF_XS + (size_t)cands[i] * (131072 + 524288);
        if (need <= ws_size) { CT = cands[i]; break; }
    }
    float* xw = (float*)(ws + OFF_XS + (size_t)CT * 131072);

    prep_wt<<<dim3(64, 16), dim3(32, 8), 0, stream>>>(Wx, wxt, wxt + (size_t)V_ * KW_);
    prep_wt<<<dim3(64, 16), dim3(32, 8), 0, stream>>>(Wh, wht, wht + (size_t)V_ * KW_);
    prep_h0<<<128, 256, 0, stream>>>(h0, hs, cs);

    for (int c0 = 0; c0 < T_; c0 += CT) {
        xsplit<<<256, 256, 0, stream>>>(x, xs, c0, CT);
        xw_gemm<<<256, 256, 0, stream>>>(xs, wxt, b, xw, CT);
        for (int tl = 0; tl < CT; ++tl) {
            lstm_step<<<64, 256, 0, stream>>>(wht, hs, cs, xw, out, c0 + tl, tl);
        }
    }
}